// Round 1
// baseline (23.705 us; speedup 1.0000x reference)
//
#include <hip/hip_runtime.h>

#define BB 8
#define SS 4096
#define DD 64
#define NH 8
#define NBKT 64
#define OUT_V_ELEMS (BB*SS*DD)   // 2097152 floats, then buckets (BB*NH*SS = 262144 floats)

// Block: 256 threads. Grid: 1024 blocks = B(8) * h-half(2) * token-chunk(64 of 64 tokens).
// LDS: rot_s [64 f][128 hi] = 32KB ; qk_s transposed [64 f][64 tt] pad->68 = 17KB. 49KB -> 3 blocks/CU.
__global__ __launch_bounds__(256) void lsh_hash_kernel(
    const float* __restrict__ qk,
    const float* __restrict__ v,
    const float* __restrict__ rot,
    float* __restrict__ out)
{
    __shared__ float rot_s[64 * 128];
    __shared__ float qk_s[64 * 68];

    const int tid = threadIdx.x;
    const int blk = blockIdx.x;
    const int b   = blk >> 7;        // 0..7
    const int r   = blk & 127;
    const int hh  = r >> 6;          // 0..1  (hash half: hashes hh*4 .. hh*4+3)
    const int tc  = r & 63;          // 0..63 (token chunk)
    const int t0  = tc * 64;

    // ---- fused v -> out[0] copy (output 0 == v exactly; see analysis) ----
    {
        const float4* v4 = (const float4*)v;
        float4*       o4 = (float4*)out;
        const int base = blk * 512 + tid;     // 1024 blocks * 512 float4 = 2M floats
        o4[base]       = v4[base];
        o4[base + 256] = v4[base + 256];
    }

    // ---- stage rotations for this h-half: rot_s[f*128 + hi] = rot[f*256 + hh*128 + hi] ----
    {
        const float4* rg = (const float4*)rot;
#pragma unroll
        for (int k = 0; k < 8; ++k) {
            const int p = tid + k * 256;      // 2048 float4s
            const int f = p >> 5, q = p & 31;
            const float4 rr = rg[f * 64 + hh * 32 + q];
            *(float4*)&rot_s[f * 128 + q * 4] = rr;
        }
    }
    // ---- stage qk tile transposed: qk_s[f*68 + tt] = qk[b, t0+tt, f] ----
    {
        const float4* qg = (const float4*)qk;
#pragma unroll
        for (int k = 0; k < 4; ++k) {
            const int p  = tid + k * 256;     // 1024 float4s
            const int tt = p >> 4, fq = p & 15;
            const float4 g = qg[(b * SS + t0 + tt) * 16 + fq];
            qk_s[(fq * 4 + 0) * 68 + tt] = g.x;
            qk_s[(fq * 4 + 1) * 68 + tt] = g.y;
            qk_s[(fq * 4 + 2) * 68 + tt] = g.z;
            qk_s[(fq * 4 + 3) * 68 + tt] = g.w;
        }
    }
    __syncthreads();

    // ---- register-tiled outer product: thread = (tg: 4 tokens, hg: 8 candidate dirs) ----
    const int tg    = tid & 15;      // token group: tokens t0 + 4*tg .. +3
    const int hg    = tid >> 4;      // 0..15 : hl = hg>>2 (hash-local), i-base = (hg&3)*8
    const int hl    = hg >> 2;
    const int ibase = (hg & 3) * 8;
    const int hglob = hh * 4 + hl;   // global hash index 0..7

    float acc[4][8];
#pragma unroll
    for (int a = 0; a < 4; ++a)
#pragma unroll
        for (int c = 0; c < 8; ++c) acc[a][c] = 0.0f;

#pragma unroll 4
    for (int f = 0; f < 64; ++f) {
        const float4 q4 = *(const float4*)&qk_s[f * 68 + tg * 4];
        const float4 r0 = *(const float4*)&rot_s[f * 128 + hg * 8];
        const float4 r1 = *(const float4*)&rot_s[f * 128 + hg * 8 + 4];
        const float qa[4] = {q4.x, q4.y, q4.z, q4.w};
        const float rr[8] = {r0.x, r0.y, r0.z, r0.w, r1.x, r1.y, r1.z, r1.w};
#pragma unroll
        for (int a = 0; a < 4; ++a)
#pragma unroll
            for (int c = 0; c < 8; ++c)
                acc[a][c] = fmaf(qa[a], rr[c], acc[a][c]);
    }

    // ---- argmax over concat([r, -r]) with first-occurrence tie-break ----
    float bq[4];
#pragma unroll
    for (int a = 0; a < 4; ++a) {
        float pv = acc[a][0]; int pi = ibase;
        float nv = -acc[a][0]; int ni = ibase;
#pragma unroll
        for (int c = 1; c < 8; ++c) {
            const float x = acc[a][c];
            if (x  > pv) { pv = x;  pi = ibase + c; }   // strict > keeps first occurrence
            if (-x > nv) { nv = -x; ni = ibase + c; }
        }
        // combine the 4 lanes (xor 16, 32) holding the other i-ranges of this hash
#pragma unroll
        for (int m = 16; m <= 32; m <<= 1) {
            const float opv = __shfl_xor(pv, m, 64);
            const int   opi = __shfl_xor(pi, m, 64);
            const float onv = __shfl_xor(nv, m, 64);
            const int   oni = __shfl_xor(ni, m, 64);
            if (opv > pv || (opv == pv && opi < pi)) { pv = opv; pi = opi; }
            if (onv > nv || (onv == nv && oni < ni)) { nv = onv; ni = oni; }
        }
        // positive half wins ties (lower concatenated index)
        const int idx = (pv >= nv) ? pi : (ni + 32);
        bq[a] = (float)(idx + hglob * NBKT);
    }

    if ((hg & 3) == 0) {
        float4 w; w.x = bq[0]; w.y = bq[1]; w.z = bq[2]; w.w = bq[3];
        *(float4*)&out[OUT_V_ELEMS + b * (NH * SS) + hglob * SS + t0 + tg * 4] = w;
    }
}

extern "C" void kernel_launch(void* const* d_in, const int* in_sizes, int n_in,
                              void* d_out, int out_size, void* d_ws, size_t ws_size,
                              hipStream_t stream) {
    const float* qk  = (const float*)d_in[0];
    const float* v   = (const float*)d_in[1];
    const float* rot = (const float*)d_in[2];
    float* out = (float*)d_out;
    hipLaunchKernelGGL(lsh_hash_kernel, dim3(1024), dim3(256), 0, stream,
                       qk, v, rot, out);
}